// Round 1
// baseline (144.098 us; speedup 1.0000x reference)
//
#include <hip/hip_runtime.h>
#include <hip/hip_bf16.h>
#include <stdint.h>

// ---- problem constants ----
#define C_CLS  100000
#define DDIM   512
#define BROWS  512
#define NT     64          // classes per block
#define KC     32          // K per pipeline step
#define NSTEP  (DDIM / KC) // 16
#define EPSN   1e-5f

typedef __attribute__((ext_vector_type(8))) short short8;
typedef __attribute__((ext_vector_type(4))) float f32x4;

__device__ inline unsigned short f2bf(float f) {
  unsigned u = __float_as_uint(f);
  u += 0x7fffu + ((u >> 16) & 1u);   // RNE
  return (unsigned short)(u >> 16);
}

__global__ void k_zero(float* acc) { *acc = 0.f; }

// Normalize each input row, convert to bf16, store row-major [512][512].
__global__ void __launch_bounds__(64) k_norm_input(const float* __restrict__ in,
                                                   unsigned short* __restrict__ xn) {
  int b = blockIdx.x;
  int lane = threadIdx.x;              // 64 lanes, 8 floats each
  const float4* row = (const float4*)(in + b * DDIM);
  float4 v0 = row[lane * 2];
  float4 v1 = row[lane * 2 + 1];
  float ss = v0.x*v0.x + v0.y*v0.y + v0.z*v0.z + v0.w*v0.w
           + v1.x*v1.x + v1.y*v1.y + v1.z*v1.z + v1.w*v1.w;
#pragma unroll
  for (int o = 32; o >= 1; o >>= 1) ss += __shfl_xor(ss, o, 64);
  float sc = 1.f / fmaxf(sqrtf(ss), EPSN);
  uint4 o4;
  o4.x = (unsigned)f2bf(v0.x*sc) | ((unsigned)f2bf(v0.y*sc) << 16);
  o4.y = (unsigned)f2bf(v0.z*sc) | ((unsigned)f2bf(v0.w*sc) << 16);
  o4.z = (unsigned)f2bf(v1.x*sc) | ((unsigned)f2bf(v1.y*sc) << 16);
  o4.w = (unsigned)f2bf(v1.z*sc) | ((unsigned)f2bf(v1.w*sc) << 16);
  *(uint4*)(xn + b * DDIM + lane * 8) = o4;
}

// Main fused kernel: block = 512 threads (8 waves). Block covers all 512 rows
// x NT=64 classes. Weight read once from HBM (f32), converted to bf16 in-flight.
__global__ void __launch_bounds__(512, 4) k_gemm(const unsigned short* __restrict__ xn,
                                                 const float* __restrict__ wt,
                                                 const float* __restrict__ bias,
                                                 float* __restrict__ acc_out) {
  __shared__ __align__(16) unsigned char sA[2][BROWS * KC * 2]; // 2 x 32 KiB
  __shared__ __align__(16) unsigned char sW[2][NT * KC * 2];    // 2 x 4 KiB
  __shared__ float sNsq[NT];
  __shared__ float sRed[8];

  const int tid  = threadIdx.x;
  const int lane = tid & 63;
  const int wv   = tid >> 6;
  const int cbase = blockIdx.x * NT;

  // ---- W staging (register path, f32 -> bf16, 8 threads per class row) ----
  const int wrow = tid >> 3;                  // 0..63 class row
  const int wkp  = tid & 7;                   // 4 floats each
  int wcls = cbase + wrow;
  if (wcls >= C_CLS) wcls = C_CLS - 1;        // clamp; masked in epilogue
  const float4* wsrc = (const float4*)(wt + (size_t)wcls * DDIM) + wkp;
  const int wslot = (wkp >> 1) ^ (wrow & 3);  // XOR bank swizzle
  const int wbyte = wrow * 64 + wslot * 16 + (wkp & 1) * 8;

  // ---- A staging via global_load_lds: linear LDS dest, pre-swizzled source ----
  const int aslot = (lane & 3) ^ ((lane >> 2) & 3);

  float wsq = 0.f;
  float4 wreg;

  f32x4 acc[4][4];
#pragma unroll
  for (int m = 0; m < 4; m++)
#pragma unroll
    for (int n = 0; n < 4; n++) acc[m][n] = (f32x4)(0.f);

  auto stageA = [&](int step, int bf) {
#pragma unroll
    for (int i = 0; i < 4; ++i) {
      int c = i * 8 + wv;                      // 32 chunks of 1 KiB
      int r = c * 16 + (lane >> 2);            // global row
      const void* src = (const unsigned char*)xn + r * (DDIM * 2) + step * (KC * 2) + aslot * 16;
      void* dst = (void*)&sA[bf][c * 1024];    // wave-uniform base; HW adds lane*16
      __builtin_amdgcn_global_load_lds(
          (const __attribute__((address_space(1))) unsigned int*)src,
          (__attribute__((address_space(3))) unsigned int*)dst, 16, 0, 0);
    }
  };
  auto loadW  = [&](int step) { wreg = wsrc[step * 8]; };
  auto writeW = [&](int bf) {
    wsq += wreg.x*wreg.x + wreg.y*wreg.y + wreg.z*wreg.z + wreg.w*wreg.w;
    uint2 d;
    d.x = (unsigned)f2bf(wreg.x) | ((unsigned)f2bf(wreg.y) << 16);
    d.y = (unsigned)f2bf(wreg.z) | ((unsigned)f2bf(wreg.w) << 16);
    *(uint2*)(&sW[bf][wbyte]) = d;
  };
  auto compute = [&](int bf) {
    short8 af[4], wf[4];
    const unsigned char* Ab = sA[bf];
    const unsigned char* Wb = sW[bf];
    const int rslot = (((lane >> 4) ^ (lane & 3)) & 3) << 4;
#pragma unroll
    for (int m = 0; m < 4; m++) {
      int r = wv * 64 + m * 16 + (lane & 15);
      af[m] = *(const short8*)(Ab + r * 64 + rslot);
    }
#pragma unroll
    for (int n = 0; n < 4; n++) {
      int rc = n * 16 + (lane & 15);
      wf[n] = *(const short8*)(Wb + rc * 64 + rslot);
    }
#pragma unroll
    for (int m = 0; m < 4; m++)
#pragma unroll
      for (int n = 0; n < 4; n++)
        acc[m][n] = __builtin_amdgcn_mfma_f32_16x16x32_bf16(af[m], wf[n], acc[m][n], 0, 0, 0);
  };

  // prologue
  loadW(0);
  stageA(0, 0);
  writeW(0);
  __syncthreads();

  int bf = 0;
#pragma unroll 1
  for (int step = 0; step < NSTEP; ++step) {
    if (step + 1 < NSTEP) {
      loadW(step + 1);
      stageA(step + 1, bf ^ 1);
    }
    compute(bf);
    if (step + 1 < NSTEP) writeW(bf ^ 1);
    __syncthreads();
    bf ^= 1;
  }

  // ---- per-class norm reduce (8 lanes per class row) ----
#pragma unroll
  for (int o = 1; o < 8; o <<= 1) wsq += __shfl_xor(wsq, o, 64);
  if ((tid & 7) == 0) sNsq[wrow] = wsq;
  __syncthreads();

  // ---- epilogue: loss over 64 acc elements / thread ----
  const float bv = bias[0];
  float sum = 0.f;
#pragma unroll
  for (int n = 0; n < 4; n++) {
    int cl = n * 16 + (lane & 15);
    float rn = 1.f / fmaxf(sqrtf(sNsq[cl]), EPSN);
    bool valid = (cbase + cl) < C_CLS;
#pragma unroll
    for (int m = 0; m < 4; m++) {
#pragma unroll
      for (int i = 0; i < 4; i++) {
        float cosv = acc[m][n][i] * rn;
        float x = fminf(fmaf(cosv, 64.f, -bv), 64.f);  // lower clip irrelevant (exp underflow)
        float z = __expf(x);
        float poly = z * fmaf(z, fmaf(z, 0.33333333f, -0.5f), 1.f); // log1p small-z
        float lg = __logf(1.f + z);
        float l = (z < 0.03125f) ? poly : lg;
        sum += valid ? l : 0.f;
      }
    }
  }
#pragma unroll
  for (int o = 32; o >= 1; o >>= 1) sum += __shfl_xor(sum, o, 64);
  if (lane == 0) sRed[wv] = sum;
  __syncthreads();
  if (tid == 0) {
    float t = 0.f;
#pragma unroll
    for (int i = 0; i < 8; i++) t += sRed[i];
    atomicAdd(acc_out, t);
  }
}

// Label correction: for each row b, replace n_loss(b, label_b) by p_loss(b, label_b),
// computed in full f32. One wave per row.
__global__ void __launch_bounds__(64) k_label(const float* __restrict__ in,
                                              const float* __restrict__ wt,
                                              const int* __restrict__ label,
                                              const float* __restrict__ bias,
                                              float* __restrict__ acc_out) {
  int b = blockIdx.x;
  int lane = threadIdx.x;
  int c = label[b];
  const float4* xr = (const float4*)(in + b * DDIM);
  const float4* wr = (const float4*)(wt + (size_t)c * DDIM);
  float dt = 0.f, sx = 0.f, sw = 0.f;
#pragma unroll
  for (int i = 0; i < 2; i++) {
    float4 x = xr[lane * 2 + i];
    float4 w = wr[lane * 2 + i];
    dt += x.x*w.x + x.y*w.y + x.z*w.z + x.w*w.w;
    sx += x.x*x.x + x.y*x.y + x.z*x.z + x.w*x.w;
    sw += w.x*w.x + w.y*w.y + w.z*w.z + w.w*w.w;
  }
#pragma unroll
  for (int o = 32; o >= 1; o >>= 1) {
    dt += __shfl_xor(dt, o, 64);
    sx += __shfl_xor(sx, o, 64);
    sw += __shfl_xor(sw, o, 64);
  }
  if (lane == 0) {
    float bv = bias[0];
    float cosv = dt / (fmaxf(sqrtf(sx), EPSN) * fmaxf(sqrtf(sw), EPSN));
    float cp = 64.f * (cosv - 0.4f) - bv;
    cp = fminf(fmaxf(cp, -64.f), 64.f);
    float pl = log1pf(expf(-cp));
    float cn = 64.f * cosv - bv;
    cn = fminf(fmaxf(cn, -64.f), 64.f);
    float nl = log1pf(expf(cn));
    atomicAdd(acc_out, pl - nl);
  }
}

__global__ void k_final(const float* acc, float* out) { out[0] = acc[0] * (1.f / 512.f); }

extern "C" void kernel_launch(void* const* d_in, const int* in_sizes, int n_in,
                              void* d_out, int out_size, void* d_ws, size_t ws_size,
                              hipStream_t stream) {
  const float* input  = (const float*)d_in[0];
  const int*   label  = (const int*)d_in[1];
  const float* weight = (const float*)d_in[2];
  const float* bias   = (const float*)d_in[3];

  float* acc = (float*)d_ws;
  unsigned short* xn = (unsigned short*)((char*)d_ws + 256);

  k_zero<<<1, 1, 0, stream>>>(acc);
  k_norm_input<<<BROWS, 64, 0, stream>>>(input, xn);
  k_gemm<<<(C_CLS + NT - 1) / NT, 512, 0, stream>>>(xn, weight, bias, acc);
  k_label<<<BROWS, 64, 0, stream>>>(input, weight, label, bias, acc);
  k_final<<<1, 1, 0, stream>>>(acc, (float*)d_out);
}

// Round 2
// 116.124 us; speedup vs baseline: 1.2409x; 1.2409x over previous
//
#include <hip/hip_runtime.h>
#include <hip/hip_bf16.h>
#include <stdint.h>

// ---- problem constants ----
#define C_CLS  100000
#define DDIM   512
#define BROWS  512
#define NT     64          // classes per block
#define KC     32          // K per step
#define NSTEP  (DDIM / KC) // 16
#define EPSN   1e-5f

typedef __attribute__((ext_vector_type(8))) short short8;
typedef __attribute__((ext_vector_type(4))) float f32x4;

__device__ inline unsigned f2bf(float f) {
  unsigned u = __float_as_uint(f);
  u += 0x7fffu + ((u >> 16) & 1u);   // RNE
  return u >> 16;
}

__global__ void k_zero(float* acc) { *acc = 0.f; }

// Normalize each input row -> bf16, store in MFMA A-fragment order:
// cell index = ((r16*16 + s)*64 + l) (16B cells), where cell l of tile
// (r16, s) holds A[row = r16*16 + (l&15)][k = s*32 + (l>>4)*8 .. +8).
__global__ void __launch_bounds__(64) k_norm_input(const float* __restrict__ in,
                                                   uint4* __restrict__ xnf) {
  int b = blockIdx.x;
  int lane = threadIdx.x;              // lane covers k = lane*8 .. +7
  const float4* row = (const float4*)(in + b * DDIM);
  float4 v0 = row[lane * 2];
  float4 v1 = row[lane * 2 + 1];
  float ss = v0.x*v0.x + v0.y*v0.y + v0.z*v0.z + v0.w*v0.w
           + v1.x*v1.x + v1.y*v1.y + v1.z*v1.z + v1.w*v1.w;
#pragma unroll
  for (int o = 32; o >= 1; o >>= 1) ss += __shfl_xor(ss, o, 64);
  float sc = 1.f / fmaxf(sqrtf(ss), EPSN);
  uint4 o4;
  o4.x = f2bf(v0.x*sc) | (f2bf(v0.y*sc) << 16);
  o4.y = f2bf(v0.z*sc) | (f2bf(v0.w*sc) << 16);
  o4.z = f2bf(v1.x*sc) | (f2bf(v1.y*sc) << 16);
  o4.w = f2bf(v1.z*sc) | (f2bf(v1.w*sc) << 16);
  // s = lane>>2, khalf = lane&3, cell l = khalf*16 + (b&15)
  int idx = ((b >> 4) * 16 + (lane >> 2)) * 64 + (lane & 3) * 16 + (b & 15);
  xnf[idx] = o4;
}

// Fused GEMM + loss. 512 threads (8 waves), block = all 512 rows x 64 classes.
// A: direct L2->reg fragment loads (no LDS). W: f32 HBM -> reg -> bf16 ->
// fragment-layout LDS (linear, conflict-free reads), 4-buffer rotation,
// ONE raw barrier per step, no vmcnt drain (2-step W prefetch stays in flight).
__global__ void __launch_bounds__(512, 4) k_gemm(const uint4* __restrict__ xnf,
                                                 const float* __restrict__ wt,
                                                 const float* __restrict__ bias,
                                                 float* __restrict__ acc_out) {
  __shared__ __align__(16) unsigned char sW[4][4096];
  __shared__ float sNsq[NT];
  __shared__ float sRed[8];

  const int tid  = threadIdx.x;
  const int lane = tid & 63;
  const int wv   = tid >> 6;
  const int cbase = blockIdx.x * NT;

  // W staging: thread t handles class cls = t>>3, k-quad q = t&7 (4 floats)
  const int cls = tid >> 3;
  const int q   = tid & 7;
  int wcls = cbase + cls;
  if (wcls >= C_CLS) wcls = C_CLS - 1;          // clamp; masked in epilogue
  const float4* wsrc = (const float4*)(wt + (size_t)wcls * DDIM) + q;
  // fragment-layout LDS byte: cell (n = cls>>4, l = (q>>1)*16 + (cls&15)), half q&1
  const int wbyte = ((cls >> 4) * 64 + (q >> 1) * 16 + (cls & 15)) * 16 + (q & 1) * 8;

  float wsq = 0.f;
  f32x4 acc[4][4];
#pragma unroll
  for (int m = 0; m < 4; m++)
#pragma unroll
    for (int n = 0; n < 4; n++) acc[m][n] = (f32x4)(0.f);

  auto cvt_write = [&](const float4& w, int bufi) {
    wsq += w.x*w.x + w.y*w.y + w.z*w.z + w.w*w.w;
    uint2 d;
    d.x = f2bf(w.x) | (f2bf(w.y) << 16);
    d.y = f2bf(w.z) | (f2bf(w.w) << 16);
    *(uint2*)(&sW[bufi][wbyte]) = d;
  };
  auto barrier = [&]() {
    __builtin_amdgcn_sched_barrier(0);
    asm volatile("s_waitcnt lgkmcnt(0)" ::: "memory");
    __builtin_amdgcn_s_barrier();
    __builtin_amdgcn_sched_barrier(0);
  };
  // step s: wcur holds W(s+1) -> write buf[(s+1)&3]; load W(s+2) -> wnext;
  // barrier; compute from buf[s&3] with direct-loaded A frags.
  auto do_step = [&](int s, float4& wcur, float4& wnext) {
    short8 af[4];
#pragma unroll
    for (int m = 0; m < 4; m++) {
      int idx = ((wv * 4 + m) * 16 + s) * 64 + lane;
      af[m] = *(const short8*)&xnf[idx];
    }
    if (s + 2 < NSTEP) wnext = wsrc[(s + 2) * 8];
    if (s + 1 < NSTEP) cvt_write(wcur, (s + 1) & 3);
    barrier();
    const unsigned char* Wb = sW[s & 3];
#pragma unroll
    for (int n = 0; n < 4; n++) {
      short8 wf = *(const short8*)(Wb + (n * 64 + lane) * 16);
#pragma unroll
      for (int m = 0; m < 4; m++)
        acc[m][n] = __builtin_amdgcn_mfma_f32_16x16x32_bf16(af[m], wf, acc[m][n], 0, 0, 0);
    }
  };

  // prologue: buf0 <- W0; wB <- W1 in flight
  float4 wA = wsrc[0];
  float4 wB = wsrc[8];
  cvt_write(wA, 0);
  barrier();

#pragma unroll 1
  for (int s = 0; s < NSTEP; s += 2) {
    do_step(s,     wB, wA);
    do_step(s + 1, wA, wB);
  }

  // ---- per-class norm^2 reduce (8 staging threads per class) ----
#pragma unroll
  for (int o = 1; o < 8; o <<= 1) wsq += __shfl_xor(wsq, o, 64);
  if ((tid & 7) == 0) sNsq[cls] = wsq;
  __syncthreads();

  // ---- epilogue: loss over 64 acc elements / thread ----
  const float bv = bias[0];
  float sum = 0.f;
#pragma unroll
  for (int n = 0; n < 4; n++) {
    int cl = n * 16 + (lane & 15);
    float rn = 1.f / fmaxf(sqrtf(sNsq[cl]), EPSN);
    bool valid = (cbase + cl) < C_CLS;
#pragma unroll
    for (int m = 0; m < 4; m++) {
#pragma unroll
      for (int i = 0; i < 4; i++) {
        float cosv = acc[m][n][i] * rn;
        float x = fminf(fmaf(cosv, 64.f, -bv), 64.f); // lower clip irrelevant (exp underflow)
        float z = __expf(x);
        float l = z * fmaf(z, fmaf(z, 0.33333333f, -0.5f), 1.f); // log1p, z small
        if (z > 0.03125f) l = __logf(1.f + z);        // rare branch (~1e-4 of lanes)
        sum += valid ? l : 0.f;
      }
    }
  }
#pragma unroll
  for (int o = 32; o >= 1; o >>= 1) sum += __shfl_xor(sum, o, 64);
  if (lane == 0) sRed[wv] = sum;
  __syncthreads();
  if (tid == 0) {
    float t = 0.f;
#pragma unroll
    for (int i = 0; i < 8; i++) t += sRed[i];
    atomicAdd(acc_out, t);
  }
}

// Label correction: replace n_loss(b, label_b) by p_loss(b, label_b), full f32.
__global__ void __launch_bounds__(64) k_label(const float* __restrict__ in,
                                              const float* __restrict__ wt,
                                              const int* __restrict__ label,
                                              const float* __restrict__ bias,
                                              float* __restrict__ acc_out) {
  int b = blockIdx.x;
  int lane = threadIdx.x;
  int c = label[b];
  const float4* xr = (const float4*)(in + b * DDIM);
  const float4* wr = (const float4*)(wt + (size_t)c * DDIM);
  float dt = 0.f, sx = 0.f, sw = 0.f;
#pragma unroll
  for (int i = 0; i < 2; i++) {
    float4 x = xr[lane * 2 + i];
    float4 w = wr[lane * 2 + i];
    dt += x.x*w.x + x.y*w.y + x.z*w.z + x.w*w.w;
    sx += x.x*x.x + x.y*x.y + x.z*x.z + x.w*x.w;
    sw += w.x*w.x + w.y*w.y + w.z*w.z + w.w*w.w;
  }
#pragma unroll
  for (int o = 32; o >= 1; o >>= 1) {
    dt += __shfl_xor(dt, o, 64);
    sx += __shfl_xor(sx, o, 64);
    sw += __shfl_xor(sw, o, 64);
  }
  if (lane == 0) {
    float bv = bias[0];
    float cosv = dt / (fmaxf(sqrtf(sx), EPSN) * fmaxf(sqrtf(sw), EPSN));
    float cp = 64.f * (cosv - 0.4f) - bv;
    cp = fminf(fmaxf(cp, -64.f), 64.f);
    float pl = log1pf(expf(-cp));
    float cn = 64.f * cosv - bv;
    cn = fminf(fmaxf(cn, -64.f), 64.f);
    float nl = log1pf(expf(cn));
    atomicAdd(acc_out, pl - nl);
  }
}

__global__ void k_final(const float* acc, float* out) { out[0] = acc[0] * (1.f / 512.f); }

extern "C" void kernel_launch(void* const* d_in, const int* in_sizes, int n_in,
                              void* d_out, int out_size, void* d_ws, size_t ws_size,
                              hipStream_t stream) {
  const float* input  = (const float*)d_in[0];
  const int*   label  = (const int*)d_in[1];
  const float* weight = (const float*)d_in[2];
  const float* bias   = (const float*)d_in[3];

  float* acc = (float*)d_ws;
  uint4* xnf = (uint4*)((char*)d_ws + 256);

  k_zero<<<1, 1, 0, stream>>>(acc);
  k_norm_input<<<BROWS, 64, 0, stream>>>(input, xnf);
  k_gemm<<<(C_CLS + NT - 1) / NT, 512, 0, stream>>>(xnf, weight, bias, acc);
  k_label<<<BROWS, 64, 0, stream>>>(input, weight, label, bias, acc);
  k_final<<<1, 1, 0, stream>>>(acc, (float*)d_out);
}